// Round 2
// baseline (1810.450 us; speedup 1.0000x reference)
//
#include <hip/hip_runtime.h>

typedef float f32x4 __attribute__((ext_vector_type(4)));
typedef short short8 __attribute__((ext_vector_type(8)));

#define NN 4096
#define HB 32               // half batch
#define FD 66
#define ROW_E 2112          // HB*FD f32 per node row (half batch)
#define ROW_Q 528           // f32x4 quads per row
#define XSW 8650752ull      // f32 words per xs buffer (NN*ROW_E)
#define KP 352              // padded K (330 real)
#define KSTEPS 11

__device__ __forceinline__ ushort f2bf(float f){ uint i = __float_as_uint(f); return (ushort)((i + 0x7fffu + ((i >> 16) & 1u)) >> 16); }
__device__ __forceinline__ float bf2f(ushort u){ return __uint_as_float((uint)u << 16); }
__device__ __forceinline__ float sigm(float x){ return 1.0f / (1.0f + __expf(-x)); }
__device__ __forceinline__ float tanh_fast(float x){
    x = fminf(20.0f, fmaxf(-20.0f, x));
    float t = __expf(-2.0f * x);
    return (1.0f - t) / (1.0f + t);
}

// ---------------- zero scratch (cnt+fill), graph-capture-safe ---------------
__global__ void zero_k(int* __restrict__ p){ p[blockIdx.x * 256 + threadIdx.x] = 0; }

// ------- weight transform: Wt_hi/lo[o][k], k = m*66+f, bf16 hi/lo split -----
__global__ void wtbuild_k(const float* __restrict__ Wru, const float* __restrict__ Wc,
                          ushort* __restrict__ ru_hi, ushort* __restrict__ ru_lo,
                          ushort* __restrict__ c_hi,  ushort* __restrict__ c_lo)
{
    int idx = blockIdx.x * 256 + threadIdx.x;   // 192*352 exact
    float w = 0.0f;
    if (idx < 128 * KP) {
        int o = idx / KP, k = idx - o * KP;
        if (k < 330) { int m = k / FD, f = k - m * FD; w = Wru[(size_t)(f * 5 + m) * 128 + o]; }
        ushort hi = f2bf(w);
        ushort lo = f2bf(w - bf2f(hi));
        ru_hi[(size_t)o * KP + k] = hi;
        ru_lo[(size_t)o * KP + k] = lo;
    } else {
        int j = idx - 128 * KP;
        int o = j / KP, k = j - o * KP;
        if (k < 330) { int m = k / FD, f = k - m * FD; w = Wc[(size_t)(f * 5 + m) * 64 + o]; }
        ushort hi = f2bf(w);
        ushort lo = f2bf(w - bf2f(hi));
        c_hi[(size_t)o * KP + k] = hi;
        c_lo[(size_t)o * KP + k] = lo;
    }
}

// ---------------- CSR build ------------------------------------------------
__global__ void count_k(const int* __restrict__ rows, int* __restrict__ cnt)
{
    int i = blockIdx.x * 256 + threadIdx.x;     // 2*65536 exact
    int s = i >> 16;
    atomicAdd(&cnt[(s << 12) + rows[i]], 1);
}

__global__ __launch_bounds__(1024) void scan_k(const int* __restrict__ cnt, int* __restrict__ rp)
{
    int s = blockIdx.x;
    const int* c = cnt + (s << 12);
    int* r = rp + s * 4097;
    __shared__ int sd[1024];
    int tid = threadIdx.x;
    int i0 = tid * 4;
    int a0 = c[i0], a1 = c[i0 + 1], a2 = c[i0 + 2], a3 = c[i0 + 3];
    sd[tid] = a0 + a1 + a2 + a3;
    __syncthreads();
    for (int off = 1; off < 1024; off <<= 1) {
        int v = (tid >= off) ? sd[tid - off] : 0;
        __syncthreads();
        sd[tid] += v;
        __syncthreads();
    }
    int base = tid ? sd[tid - 1] : 0;
    r[i0] = base; r[i0 + 1] = base + a0; r[i0 + 2] = base + a0 + a1; r[i0 + 3] = base + a0 + a1 + a2;
    if (tid == 1023) r[4096] = sd[1023];
}

__global__ void scatter_k(const int* __restrict__ rows, const int* __restrict__ cols,
                          const float* __restrict__ vals, const int* __restrict__ rp,
                          int* __restrict__ fill, int* __restrict__ sc, float* __restrict__ sv)
{
    int i = blockIdx.x * 256 + threadIdx.x;     // 2*65536 exact
    int s = i >> 16;
    int r = rows[i];
    int pos = rp[s * 4097 + r] + atomicAdd(&fill[(s << 12) + r], 1);
    sc[(s << 16) + pos] = cols[i];
    sv[(s << 16) + pos] = vals[i];
}

// ---------------- x0 build (f32): x0[n][bl*66+f], half batch h --------------
__global__ void x0build_k(const float* __restrict__ in, const float* __restrict__ hx,
                          float* __restrict__ x0, int h)
{
    int i = blockIdx.x * 256 + threadIdx.x;     // NN*1056 exact (pairs)
    int e0 = i * 2;
    int n = e0 / ROW_E;
    int rem = e0 - n * ROW_E;
    int bl = rem / FD;
    int f = rem - bl * FD;                      // even
    int b = h * HB + bl;
    float v0 = (f < 2) ? in[(size_t)b * 8192 + n * 2 + f]
                       : hx[(size_t)b * 262144 + (size_t)n * 64 + (f - 2)];
    int f1 = f + 1;
    float v1 = (f1 < 2) ? in[(size_t)b * 8192 + n * 2 + f1]
                        : hx[(size_t)b * 262144 + (size_t)n * 64 + (f1 - 2)];
    float2 ov; ov.x = v0; ov.y = v1;
    *(float2*)(x0 + e0) = ov;
}

// ---------------- SpMM (CSR row-gather, f32), both supports per launch ------
__global__ __launch_bounds__(256) void spmm_k(const float* __restrict__ src0, const float* __restrict__ src1,
                                              float* __restrict__ dst0, float* __restrict__ dst1,
                                              const float* __restrict__ prev,
                                              const int* __restrict__ rp, const int* __restrict__ sc,
                                              const float* __restrict__ sv, int cheb)
{
    const int r = blockIdx.x, s = blockIdx.y;
    const float* __restrict__ x = s ? src1 : src0;
    float* __restrict__ dst = s ? dst1 : dst0;
    const int p0 = rp[s * 4097 + r], p1 = rp[s * 4097 + r + 1];
    const int* cs = sc + (s << 16);
    const float* vs = sv + (s << 16);
    for (int q = threadIdx.x; q < ROW_Q; q += 256) {
        float a0 = 0.f, a1 = 0.f, a2 = 0.f, a3 = 0.f;
        for (int e = p0; e < p1; ++e) {
            const int c = cs[e];
            const float v = vs[e];
            const float4 xv = *(const float4*)(x + (size_t)c * ROW_E + (q << 2));
            a0 = fmaf(v, xv.x, a0); a1 = fmaf(v, xv.y, a1);
            a2 = fmaf(v, xv.z, a2); a3 = fmaf(v, xv.w, a3);
        }
        if (cheb) {
            const float4 pv = *(const float4*)(prev + (size_t)r * ROW_E + (q << 2));
            a0 = 2.0f * a0 - pv.x; a1 = 2.0f * a1 - pv.y;
            a2 = 2.0f * a2 - pv.z; a3 = 2.0f * a3 - pv.w;
        }
        float4 ov; ov.x = a0; ov.y = a1; ov.z = a2; ov.w = a3;
        *(float4*)(dst + (size_t)r * ROW_E + (q << 2)) = ov;
    }
}

// ------ shared staging: f32 rows -> hi/lo bf16 packed LDS -------------------
__device__ __forceinline__ void stage_hilo(const float* __restrict__ xs, int n, int tid,
                                           uint* __restrict__ Bhi, uint* __restrict__ Blo)
{
    for (int i = tid; i < HB * 15; i += 256) {  // zero K-pad words 165..179
        int bl = i / 15, t = i - bl * 15;
        Bhi[bl * 180 + 165 + t] = 0u;
        Blo[bl * 180 + 165 + t] = 0u;
    }
    for (int i = tid; i < 5 * 1056; i += 256) {
        int m = i / 1056;
        int pr = i - m * 1056;
        int bl = pr / 33, fw = pr - bl * 33;
        float2 xv = *(const float2*)(xs + (size_t)m * XSW + (size_t)n * ROW_E + bl * FD + fw * 2);
        ushort h0 = f2bf(xv.x); ushort l0 = f2bf(xv.x - bf2f(h0));
        ushort h1 = f2bf(xv.y); ushort l1 = f2bf(xv.y - bf2f(h1));
        Bhi[bl * 180 + m * 33 + fw] = (uint)h0 | ((uint)h1 << 16);
        Blo[bl * 180 + m * 33 + fw] = (uint)l0 | ((uint)l1 << 16);
    }
}

// ---------------- gconv1 matmul + sigmoid; u->out, r*hx->xs0 ----------------
__global__ __launch_bounds__(256) void mm_ru_k(const float* __restrict__ xs,
                                               const ushort* __restrict__ whi, const ushort* __restrict__ wlo,
                                               const float* __restrict__ bru, const float* __restrict__ hx,
                                               float* __restrict__ uout, float* __restrict__ xs0w, int h)
{
    const int n = blockIdx.x;
    const int tid = threadIdx.x;
    const int lane = tid & 63, wave = tid >> 6;
    __shared__ uint Bhi[HB * 180];
    __shared__ uint Blo[HB * 180];
    __shared__ float hxs[HB][68];

    stage_hilo(xs, n, tid, Bhi, Blo);
    for (int i = tid; i < HB * 64; i += 256) {
        int bl = i >> 6, j = i & 63;
        hxs[bl][j] = hx[(size_t)(h * HB + bl) * 262144 + (size_t)n * 64 + j];
    }
    __syncthreads();

    const int ob = wave * 32 + (lane & 15);
    const int ksub = (lane >> 4) * 8;
    const int brow = lane & 15;
    f32x4 acc[2][2] = {};

    #pragma unroll 1
    for (int p = 0; p < 3; ++p) {
        const ushort* Aw = (p == 2) ? wlo : whi;
        const ushort* Bl16 = (const ushort*)((p == 1) ? Blo : Bhi);
        short8 A[2][KSTEPS];
        #pragma unroll
        for (int t = 0; t < 2; ++t)
            #pragma unroll
            for (int ks = 0; ks < KSTEPS; ++ks)
                A[t][ks] = *(const short8*)(Aw + (size_t)(ob + t * 16) * KP + ks * 32 + ksub);
        #pragma unroll
        for (int ks = 0; ks < KSTEPS; ++ks) {
            short8 Bf[2];
            #pragma unroll
            for (int bt = 0; bt < 2; ++bt)
                Bf[bt] = *(const short8*)(Bl16 + (bt * 16 + brow) * 360 + ks * 32 + ksub);
            #pragma unroll
            for (int t = 0; t < 2; ++t)
                #pragma unroll
                for (int bt = 0; bt < 2; ++bt)
                    acc[t][bt] = __builtin_amdgcn_mfma_f32_16x16x32_bf16(A[t][ks], Bf[bt], acc[t][bt], 0, 0, 0);
        }
    }

    const int g = lane >> 4, bcol = lane & 15;
    #pragma unroll
    for (int t = 0; t < 2; ++t) {
        const int o = wave * 32 + t * 16 + g * 4;
        const float bb0 = bru[o], bb1 = bru[o + 1], bb2 = bru[o + 2], bb3 = bru[o + 3];
        #pragma unroll
        for (int bt = 0; bt < 2; ++bt) {
            const int bl = bt * 16 + bcol;
            float s0 = sigm(acc[t][bt][0] + bb0);
            float s1 = sigm(acc[t][bt][1] + bb1);
            float s2 = sigm(acc[t][bt][2] + bb2);
            float s3 = sigm(acc[t][bt][3] + bb3);
            if (o < 64) {   // r-part: write r*hx into xs0 state features (f32)
                float* dw = xs0w + (size_t)n * ROW_E + bl * FD + 2 + o;
                float2 w0; w0.x = s0 * hxs[bl][o + 0]; w0.y = s1 * hxs[bl][o + 1];
                float2 w1; w1.x = s2 * hxs[bl][o + 2]; w1.y = s3 * hxs[bl][o + 3];
                *(float2*)(dw) = w0;
                *(float2*)(dw + 2) = w1;
            } else {        // u-part -> d_out (temporary storage)
                f32x4 uv = {s0, s1, s2, s3};
                *(f32x4*)(uout + (size_t)(h * HB + bl) * 262144 + (size_t)n * 64 + (o - 64)) = uv;
            }
        }
    }
}

// ---------------- gconv2 matmul + tanh + final GRU combine ------------------
__global__ __launch_bounds__(256) void mm_c_k(const float* __restrict__ xs,
                                              const ushort* __restrict__ whi, const ushort* __restrict__ wlo,
                                              const float* __restrict__ bc, const float* __restrict__ hx,
                                              float* __restrict__ out, int h)
{
    const int n = blockIdx.x;
    const int tid = threadIdx.x;
    const int lane = tid & 63, wave = tid >> 6;
    __shared__ uint Bhi[HB * 180];
    __shared__ uint Blo[HB * 180];
    __shared__ float hxs[HB][68];

    stage_hilo(xs, n, tid, Bhi, Blo);
    for (int i = tid; i < HB * 64; i += 256) {
        int bl = i >> 6, j = i & 63;
        hxs[bl][j] = hx[(size_t)(h * HB + bl) * 262144 + (size_t)n * 64 + j];
    }
    __syncthreads();

    const int ob = wave * 16 + (lane & 15);
    const int ksub = (lane >> 4) * 8;
    const int brow = lane & 15;
    f32x4 acc[2] = {};

    #pragma unroll 1
    for (int p = 0; p < 3; ++p) {
        const ushort* Aw = (p == 2) ? wlo : whi;
        const ushort* Bl16 = (const ushort*)((p == 1) ? Blo : Bhi);
        short8 A[KSTEPS];
        #pragma unroll
        for (int ks = 0; ks < KSTEPS; ++ks)
            A[ks] = *(const short8*)(Aw + (size_t)ob * KP + ks * 32 + ksub);
        #pragma unroll
        for (int ks = 0; ks < KSTEPS; ++ks) {
            short8 Bf[2];
            #pragma unroll
            for (int bt = 0; bt < 2; ++bt)
                Bf[bt] = *(const short8*)(Bl16 + (bt * 16 + brow) * 360 + ks * 32 + ksub);
            #pragma unroll
            for (int bt = 0; bt < 2; ++bt)
                acc[bt] = __builtin_amdgcn_mfma_f32_16x16x32_bf16(A[ks], Bf[bt], acc[bt], 0, 0, 0);
        }
    }

    const int g = lane >> 4, bcol = lane & 15;
    const int o = wave * 16 + g * 4;
    const float bb0 = bc[o], bb1 = bc[o + 1], bb2 = bc[o + 2], bb3 = bc[o + 3];
    #pragma unroll
    for (int bt = 0; bt < 2; ++bt) {
        const int bl = bt * 16 + bcol;
        float c0 = tanh_fast(acc[bt][0] + bb0);
        float c1 = tanh_fast(acc[bt][1] + bb1);
        float c2 = tanh_fast(acc[bt][2] + bb2);
        float c3 = tanh_fast(acc[bt][3] + bb3);
        float* p = out + (size_t)(h * HB + bl) * 262144 + (size_t)n * 64 + o;
        f32x4 uv = *(const f32x4*)p;
        f32x4 ov;
        ov[0] = uv[0] * hxs[bl][o + 0] + (1.0f - uv[0]) * c0;
        ov[1] = uv[1] * hxs[bl][o + 1] + (1.0f - uv[1]) * c1;
        ov[2] = uv[2] * hxs[bl][o + 2] + (1.0f - uv[2]) * c2;
        ov[3] = uv[3] * hxs[bl][o + 3] + (1.0f - uv[3]) * c3;
        *(f32x4*)p = ov;
    }
}

// ---------------------------------------------------------------------------
extern "C" void kernel_launch(void* const* d_in, const int* in_sizes, int n_in,
                              void* d_out, int out_size, void* d_ws, size_t ws_size,
                              hipStream_t stream)
{
    (void)in_sizes; (void)n_in; (void)out_size; (void)ws_size;
    const float* inputs  = (const float*)d_in[0];
    const float* hx      = (const float*)d_in[1];
    const int*   sup_rows= (const int*)d_in[2];
    const int*   sup_cols= (const int*)d_in[3];
    const float* sup_vals= (const float*)d_in[4];
    const float* W_ru    = (const float*)d_in[5];
    const float* b_ru    = (const float*)d_in[6];
    const float* W_c     = (const float*)d_in[7];
    const float* b_c     = (const float*)d_in[8];
    float* out = (float*)d_out;

    char* ws = (char*)d_ws;
    float* xs = (float*)ws;                                 // 5 f32 buffers (half batch)
    size_t off = 5ull * 34603008ull;                        // 173,015,040
    ushort* wru_hi = (ushort*)(ws + off); off += 90112;
    ushort* wru_lo = (ushort*)(ws + off); off += 90112;
    ushort* wc_hi  = (ushort*)(ws + off); off += 45056;
    ushort* wc_lo  = (ushort*)(ws + off); off += 45056;
    int* row_ptr   = (int*)(ws + off);    off += 32800;     // 2*4097*4 rounded up
    int* cntfill   = (int*)(ws + off);    off += 65536;     // cnt[8192] + fill[8192]
    int* scols     = (int*)(ws + off);    off += 524288;
    float* svals   = (float*)(ws + off);  off += 524288;

    float* xs0 = xs;
    float* xs1 = xs + 1 * XSW;
    float* xs2 = xs + 2 * XSW;
    float* xs3 = xs + 3 * XSW;
    float* xs4 = xs + 4 * XSW;
    int* fill = cntfill + 8192;

    zero_k<<<64, 256, 0, stream>>>(cntfill);
    wtbuild_k<<<264, 256, 0, stream>>>(W_ru, W_c, wru_hi, wru_lo, wc_hi, wc_lo);
    count_k<<<512, 256, 0, stream>>>(sup_rows, cntfill);
    scan_k<<<2, 1024, 0, stream>>>(cntfill, row_ptr);
    scatter_k<<<512, 256, 0, stream>>>(sup_rows, sup_cols, sup_vals, row_ptr, fill, scols, svals);

    dim3 sg(NN, 2);
    for (int h = 0; h < 2; ++h) {
        x0build_k<<<16896, 256, 0, stream>>>(inputs, hx, xs0, h);
        // gconv1 diffusion
        spmm_k<<<sg, 256, 0, stream>>>(xs0, xs0, xs1, xs3, xs0, row_ptr, scols, svals, 0);
        spmm_k<<<sg, 256, 0, stream>>>(xs1, xs3, xs2, xs4, xs0, row_ptr, scols, svals, 1);
        // gconv1 matmul: u -> out, r*hx -> xs0 state part
        mm_ru_k<<<NN, 256, 0, stream>>>(xs, wru_hi, wru_lo, b_ru, hx, out, xs0, h);
        // gconv2 diffusion (xs0 now holds [inputs, r*hx])
        spmm_k<<<sg, 256, 0, stream>>>(xs0, xs0, xs1, xs3, xs0, row_ptr, scols, svals, 0);
        spmm_k<<<sg, 256, 0, stream>>>(xs1, xs3, xs2, xs4, xs0, row_ptr, scols, svals, 1);
        // gconv2 matmul + tanh + final GRU combine
        mm_c_k<<<NN, 256, 0, stream>>>(xs, wc_hi, wc_lo, b_c, hx, out, h);
    }
}

// Round 3
// 1626.699 us; speedup vs baseline: 1.1130x; 1.1130x over previous
//
#include <hip/hip_runtime.h>

typedef float f32x4 __attribute__((ext_vector_type(4)));
typedef float f32x2 __attribute__((ext_vector_type(2)));
typedef short short8 __attribute__((ext_vector_type(8)));

#define NN 4096
#define HB 32               // half batch
#define FD 66
#define ROW_E 2112          // HB*FD f32 per node row (half batch)
#define XSW 8650752ull      // f32 words per xs buffer (NN*ROW_E)
#define KP 352              // padded K (330 real)
#define KSTEPS 11

__device__ __forceinline__ ushort f2bf(float f){ uint i = __float_as_uint(f); return (ushort)((i + 0x7fffu + ((i >> 16) & 1u)) >> 16); }
__device__ __forceinline__ float bf2f(ushort u){ return __uint_as_float((uint)u << 16); }
__device__ __forceinline__ float sigm(float x){ return 1.0f / (1.0f + __expf(-x)); }
__device__ __forceinline__ float tanh_fast(float x){
    x = fminf(20.0f, fmaxf(-20.0f, x));
    float t = __expf(-2.0f * x);
    return (1.0f - t) / (1.0f + t);
}

// ---------------- zero scratch (cnt+fill), graph-capture-safe ---------------
__global__ void zero_k(int* __restrict__ p){ p[blockIdx.x * 256 + threadIdx.x] = 0; }

// ------- weight transform: Wt_hi/lo[o][k], k = m*66+f, bf16 hi/lo split -----
__global__ void wtbuild_k(const float* __restrict__ Wru, const float* __restrict__ Wc,
                          ushort* __restrict__ ru_hi, ushort* __restrict__ ru_lo,
                          ushort* __restrict__ c_hi,  ushort* __restrict__ c_lo)
{
    int idx = blockIdx.x * 256 + threadIdx.x;   // 192*352 exact
    float w = 0.0f;
    if (idx < 128 * KP) {
        int o = idx / KP, k = idx - o * KP;
        if (k < 330) { int m = k / FD, f = k - m * FD; w = Wru[(size_t)(f * 5 + m) * 128 + o]; }
        ushort hi = f2bf(w);
        ushort lo = f2bf(w - bf2f(hi));
        ru_hi[(size_t)o * KP + k] = hi;
        ru_lo[(size_t)o * KP + k] = lo;
    } else {
        int j = idx - 128 * KP;
        int o = j / KP, k = j - o * KP;
        if (k < 330) { int m = k / FD, f = k - m * FD; w = Wc[(size_t)(f * 5 + m) * 64 + o]; }
        ushort hi = f2bf(w);
        ushort lo = f2bf(w - bf2f(hi));
        c_hi[(size_t)o * KP + k] = hi;
        c_lo[(size_t)o * KP + k] = lo;
    }
}

// ---------------- CSR build ------------------------------------------------
__global__ void count_k(const int* __restrict__ rows, int* __restrict__ cnt)
{
    int i = blockIdx.x * 256 + threadIdx.x;     // 2*65536 exact
    int s = i >> 16;
    atomicAdd(&cnt[(s << 12) + rows[i]], 1);
}

__global__ __launch_bounds__(1024) void scan_k(const int* __restrict__ cnt, int* __restrict__ rp)
{
    int s = blockIdx.x;
    const int* c = cnt + (s << 12);
    int* r = rp + s * 4097;
    __shared__ int sd[1024];
    int tid = threadIdx.x;
    int i0 = tid * 4;
    int a0 = c[i0], a1 = c[i0 + 1], a2 = c[i0 + 2], a3 = c[i0 + 3];
    sd[tid] = a0 + a1 + a2 + a3;
    __syncthreads();
    for (int off = 1; off < 1024; off <<= 1) {
        int v = (tid >= off) ? sd[tid - off] : 0;
        __syncthreads();
        sd[tid] += v;
        __syncthreads();
    }
    int base = tid ? sd[tid - 1] : 0;
    r[i0] = base; r[i0 + 1] = base + a0; r[i0 + 2] = base + a0 + a1; r[i0 + 3] = base + a0 + a1 + a2;
    if (tid == 1023) r[4096] = sd[1023];
}

__global__ void scatter_k(const int* __restrict__ rows, const int* __restrict__ cols,
                          const float* __restrict__ vals, const int* __restrict__ rp,
                          int* __restrict__ fill, int* __restrict__ sc, float* __restrict__ sv)
{
    int i = blockIdx.x * 256 + threadIdx.x;     // 2*65536 exact
    int s = i >> 16;
    int r = rows[i];
    int pos = rp[s * 4097 + r] + atomicAdd(&fill[(s << 12) + r], 1);
    sc[(s << 16) + pos] = cols[i];
    sv[(s << 16) + pos] = vals[i];
}

// ---------------- x0 build (f32): x0[n][bl*66+f], half batch h --------------
__global__ void x0build_k(const float* __restrict__ in, const float* __restrict__ hx,
                          float* __restrict__ x0, int h)
{
    int i = blockIdx.x * 256 + threadIdx.x;     // NN*1056 exact (pairs)
    int e0 = i * 2;
    int n = e0 / ROW_E;
    int rem = e0 - n * ROW_E;
    int bl = rem / FD;
    int f = rem - bl * FD;                      // even
    int b = h * HB + bl;
    float v0 = (f < 2) ? in[(size_t)b * 8192 + n * 2 + f]
                       : hx[(size_t)b * 262144 + (size_t)n * 64 + (f - 2)];
    int f1 = f + 1;
    float v1 = (f1 < 2) ? in[(size_t)b * 8192 + n * 2 + f1]
                        : hx[(size_t)b * 262144 + (size_t)n * 64 + (f1 - 2)];
    f32x2 ov; ov.x = v0; ov.y = v1;
    __builtin_nontemporal_store(ov, (f32x2*)(x0 + e0));
}

// ---------------- SpMM, feature-chunked for XCD-L2 residency ----------------
// chunk = blockIdx.x & 7 -> XCD pin (round-robin dispatch). Each XCD touches
// only cols [chunk*66*4, ...) of the source: slice = 4096*1056B = 4.33 MB ~ L2.
// wave = one row; lane -> quad chunk*66+lane; lanes 0,1 also cover quads 64,65.
__global__ __launch_bounds__(256) void spmm_k(const float* __restrict__ src0, const float* __restrict__ src1,
                                              float* __restrict__ dst0, float* __restrict__ dst1,
                                              const float* __restrict__ prev,
                                              const int* __restrict__ rp, const int* __restrict__ sc,
                                              const float* __restrict__ sv, int cheb, int supbase)
{
    const int s = supbase + blockIdx.y;
    const float* __restrict__ x = s ? src1 : src0;
    float* __restrict__ dst = s ? dst1 : dst0;
    const int chunk = blockIdx.x & 7;
    const int r = ((blockIdx.x >> 3) << 2) + (threadIdx.x >> 6);
    const int lane = threadIdx.x & 63;
    const int p0 = rp[s * 4097 + r], p1 = rp[s * 4097 + r + 1];
    const int* cs = sc + (s << 16);
    const float* vs = sv + (s << 16);
    const int q1 = chunk * 66 + lane;
    const int q2 = chunk * 66 + ((lane < 2) ? (64 + lane) : lane);  // dup for lanes>=2 (same line, no extra L2 miss)
    const size_t o1 = (size_t)q1 << 2, o2 = (size_t)q2 << 2;        // f32 offsets

    f32x4 A1 = {0,0,0,0}, B1 = {0,0,0,0}, A2 = {0,0,0,0}, B2 = {0,0,0,0};
    int e = p0;
    for (; e + 2 <= p1; e += 2) {
        const int   c0 = cs[e],     c1 = cs[e + 1];
        const float v0 = vs[e],     v1 = vs[e + 1];
        const float* r0p = x + (size_t)c0 * ROW_E;
        const float* r1p = x + (size_t)c1 * ROW_E;
        const f32x4 xa = *(const f32x4*)(r0p + o1);
        const f32x4 xb = *(const f32x4*)(r1p + o1);
        const f32x4 ya = *(const f32x4*)(r0p + o2);
        const f32x4 yb = *(const f32x4*)(r1p + o2);
        A1.x = fmaf(v0, xa.x, A1.x); A1.y = fmaf(v0, xa.y, A1.y); A1.z = fmaf(v0, xa.z, A1.z); A1.w = fmaf(v0, xa.w, A1.w);
        B1.x = fmaf(v1, xb.x, B1.x); B1.y = fmaf(v1, xb.y, B1.y); B1.z = fmaf(v1, xb.z, B1.z); B1.w = fmaf(v1, xb.w, B1.w);
        A2.x = fmaf(v0, ya.x, A2.x); A2.y = fmaf(v0, ya.y, A2.y); A2.z = fmaf(v0, ya.z, A2.z); A2.w = fmaf(v0, ya.w, A2.w);
        B2.x = fmaf(v1, yb.x, B2.x); B2.y = fmaf(v1, yb.y, B2.y); B2.z = fmaf(v1, yb.z, B2.z); B2.w = fmaf(v1, yb.w, B2.w);
    }
    if (e < p1) {
        const int   c0 = cs[e];
        const float v0 = vs[e];
        const float* r0p = x + (size_t)c0 * ROW_E;
        const f32x4 xa = *(const f32x4*)(r0p + o1);
        const f32x4 ya = *(const f32x4*)(r0p + o2);
        A1.x = fmaf(v0, xa.x, A1.x); A1.y = fmaf(v0, xa.y, A1.y); A1.z = fmaf(v0, xa.z, A1.z); A1.w = fmaf(v0, xa.w, A1.w);
        A2.x = fmaf(v0, ya.x, A2.x); A2.y = fmaf(v0, ya.y, A2.y); A2.z = fmaf(v0, ya.z, A2.z); A2.w = fmaf(v0, ya.w, A2.w);
    }
    f32x4 R1, R2;
    R1.x = A1.x + B1.x; R1.y = A1.y + B1.y; R1.z = A1.z + B1.z; R1.w = A1.w + B1.w;
    R2.x = A2.x + B2.x; R2.y = A2.y + B2.y; R2.z = A2.z + B2.z; R2.w = A2.w + B2.w;

    const size_t rbase = (size_t)r * ROW_E;
    if (cheb) {
        const f32x4 p1v = __builtin_nontemporal_load((const f32x4*)(prev + rbase + o1));
        R1.x = 2.0f * R1.x - p1v.x; R1.y = 2.0f * R1.y - p1v.y;
        R1.z = 2.0f * R1.z - p1v.z; R1.w = 2.0f * R1.w - p1v.w;
        if (lane < 2) {
            const f32x4 p2v = __builtin_nontemporal_load((const f32x4*)(prev + rbase + o2));
            R2.x = 2.0f * R2.x - p2v.x; R2.y = 2.0f * R2.y - p2v.y;
            R2.z = 2.0f * R2.z - p2v.z; R2.w = 2.0f * R2.w - p2v.w;
        }
    }
    __builtin_nontemporal_store(R1, (f32x4*)(dst + rbase + o1));
    if (lane < 2)
        __builtin_nontemporal_store(R2, (f32x4*)(dst + rbase + o2));
}

// ------ shared staging: f32 rows -> hi/lo bf16 packed LDS -------------------
__device__ __forceinline__ void stage_hilo(const float* __restrict__ xs, int n, int tid,
                                           uint* __restrict__ Bhi, uint* __restrict__ Blo)
{
    for (int i = tid; i < HB * 15; i += 256) {  // zero K-pad words 165..179
        int bl = i / 15, t = i - bl * 15;
        Bhi[bl * 180 + 165 + t] = 0u;
        Blo[bl * 180 + 165 + t] = 0u;
    }
    for (int i = tid; i < 5 * 1056; i += 256) {
        int m = i / 1056;
        int pr = i - m * 1056;
        int bl = pr / 33, fw = pr - bl * 33;
        f32x2 xv = __builtin_nontemporal_load((const f32x2*)(xs + (size_t)m * XSW + (size_t)n * ROW_E + bl * FD + fw * 2));
        ushort h0 = f2bf(xv.x); ushort l0 = f2bf(xv.x - bf2f(h0));
        ushort h1 = f2bf(xv.y); ushort l1 = f2bf(xv.y - bf2f(h1));
        Bhi[bl * 180 + m * 33 + fw] = (uint)h0 | ((uint)h1 << 16);
        Blo[bl * 180 + m * 33 + fw] = (uint)l0 | ((uint)l1 << 16);
    }
}

// ---------------- gconv1 matmul + sigmoid; u->out, r*hx->xs0 ----------------
__global__ __launch_bounds__(256) void mm_ru_k(const float* __restrict__ xs,
                                               const ushort* __restrict__ whi, const ushort* __restrict__ wlo,
                                               const float* __restrict__ bru, const float* __restrict__ hx,
                                               float* __restrict__ uout, float* __restrict__ xs0w, int h)
{
    const int n = blockIdx.x;
    const int tid = threadIdx.x;
    const int lane = tid & 63, wave = tid >> 6;
    __shared__ uint Bhi[HB * 180];
    __shared__ uint Blo[HB * 180];
    __shared__ float hxs[HB][68];

    stage_hilo(xs, n, tid, Bhi, Blo);
    for (int i = tid; i < HB * 64; i += 256) {
        int bl = i >> 6, j = i & 63;
        hxs[bl][j] = hx[(size_t)(h * HB + bl) * 262144 + (size_t)n * 64 + j];
    }
    __syncthreads();

    const int ob = wave * 32 + (lane & 15);
    const int ksub = (lane >> 4) * 8;
    const int brow = lane & 15;
    f32x4 acc[2][2] = {};

    #pragma unroll 1
    for (int p = 0; p < 3; ++p) {
        const ushort* Aw = (p == 2) ? wlo : whi;
        const ushort* Bl16 = (const ushort*)((p == 1) ? Blo : Bhi);
        short8 A[2][KSTEPS];
        #pragma unroll
        for (int t = 0; t < 2; ++t)
            #pragma unroll
            for (int ks = 0; ks < KSTEPS; ++ks)
                A[t][ks] = *(const short8*)(Aw + (size_t)(ob + t * 16) * KP + ks * 32 + ksub);
        #pragma unroll
        for (int ks = 0; ks < KSTEPS; ++ks) {
            short8 Bf[2];
            #pragma unroll
            for (int bt = 0; bt < 2; ++bt)
                Bf[bt] = *(const short8*)(Bl16 + (bt * 16 + brow) * 360 + ks * 32 + ksub);
            #pragma unroll
            for (int t = 0; t < 2; ++t)
                #pragma unroll
                for (int bt = 0; bt < 2; ++bt)
                    acc[t][bt] = __builtin_amdgcn_mfma_f32_16x16x32_bf16(A[t][ks], Bf[bt], acc[t][bt], 0, 0, 0);
        }
    }

    const int g = lane >> 4, bcol = lane & 15;
    #pragma unroll
    for (int t = 0; t < 2; ++t) {
        const int o = wave * 32 + t * 16 + g * 4;
        const float bb0 = bru[o], bb1 = bru[o + 1], bb2 = bru[o + 2], bb3 = bru[o + 3];
        #pragma unroll
        for (int bt = 0; bt < 2; ++bt) {
            const int bl = bt * 16 + bcol;
            float s0 = sigm(acc[t][bt][0] + bb0);
            float s1 = sigm(acc[t][bt][1] + bb1);
            float s2 = sigm(acc[t][bt][2] + bb2);
            float s3 = sigm(acc[t][bt][3] + bb3);
            if (o < 64) {   // r-part: write r*hx into xs0 state features (f32)
                float* dw = xs0w + (size_t)n * ROW_E + bl * FD + 2 + o;
                f32x2 w0; w0.x = s0 * hxs[bl][o + 0]; w0.y = s1 * hxs[bl][o + 1];
                f32x2 w1; w1.x = s2 * hxs[bl][o + 2]; w1.y = s3 * hxs[bl][o + 3];
                *(f32x2*)(dw) = w0;
                *(f32x2*)(dw + 2) = w1;
            } else {        // u-part -> d_out (temporary storage)
                f32x4 uv = {s0, s1, s2, s3};
                *(f32x4*)(uout + (size_t)(h * HB + bl) * 262144 + (size_t)n * 64 + (o - 64)) = uv;
            }
        }
    }
}

// ---------------- gconv2 matmul + tanh + final GRU combine ------------------
__global__ __launch_bounds__(256) void mm_c_k(const float* __restrict__ xs,
                                              const ushort* __restrict__ whi, const ushort* __restrict__ wlo,
                                              const float* __restrict__ bc, const float* __restrict__ hx,
                                              float* __restrict__ out, int h)
{
    const int n = blockIdx.x;
    const int tid = threadIdx.x;
    const int lane = tid & 63, wave = tid >> 6;
    __shared__ uint Bhi[HB * 180];
    __shared__ uint Blo[HB * 180];
    __shared__ float hxs[HB][68];

    stage_hilo(xs, n, tid, Bhi, Blo);
    for (int i = tid; i < HB * 64; i += 256) {
        int bl = i >> 6, j = i & 63;
        hxs[bl][j] = hx[(size_t)(h * HB + bl) * 262144 + (size_t)n * 64 + j];
    }
    __syncthreads();

    const int ob = wave * 16 + (lane & 15);
    const int ksub = (lane >> 4) * 8;
    const int brow = lane & 15;
    f32x4 acc[2] = {};

    #pragma unroll 1
    for (int p = 0; p < 3; ++p) {
        const ushort* Aw = (p == 2) ? wlo : whi;
        const ushort* Bl16 = (const ushort*)((p == 1) ? Blo : Bhi);
        short8 A[KSTEPS];
        #pragma unroll
        for (int ks = 0; ks < KSTEPS; ++ks)
            A[ks] = *(const short8*)(Aw + (size_t)ob * KP + ks * 32 + ksub);
        #pragma unroll
        for (int ks = 0; ks < KSTEPS; ++ks) {
            short8 Bf[2];
            #pragma unroll
            for (int bt = 0; bt < 2; ++bt)
                Bf[bt] = *(const short8*)(Bl16 + (bt * 16 + brow) * 360 + ks * 32 + ksub);
            #pragma unroll
            for (int bt = 0; bt < 2; ++bt)
                acc[bt] = __builtin_amdgcn_mfma_f32_16x16x32_bf16(A[ks], Bf[bt], acc[bt], 0, 0, 0);
        }
    }

    const int g = lane >> 4, bcol = lane & 15;
    const int o = wave * 16 + g * 4;
    const float bb0 = bc[o], bb1 = bc[o + 1], bb2 = bc[o + 2], bb3 = bc[o + 3];
    #pragma unroll
    for (int bt = 0; bt < 2; ++bt) {
        const int bl = bt * 16 + bcol;
        float c0 = tanh_fast(acc[bt][0] + bb0);
        float c1 = tanh_fast(acc[bt][1] + bb1);
        float c2 = tanh_fast(acc[bt][2] + bb2);
        float c3 = tanh_fast(acc[bt][3] + bb3);
        float* p = out + (size_t)(h * HB + bl) * 262144 + (size_t)n * 64 + o;
        f32x4 uv = *(const f32x4*)p;
        f32x4 ov;
        ov[0] = uv[0] * hxs[bl][o + 0] + (1.0f - uv[0]) * c0;
        ov[1] = uv[1] * hxs[bl][o + 1] + (1.0f - uv[1]) * c1;
        ov[2] = uv[2] * hxs[bl][o + 2] + (1.0f - uv[2]) * c2;
        ov[3] = uv[3] * hxs[bl][o + 3] + (1.0f - uv[3]) * c3;
        *(f32x4*)p = ov;
    }
}

// ---------------------------------------------------------------------------
extern "C" void kernel_launch(void* const* d_in, const int* in_sizes, int n_in,
                              void* d_out, int out_size, void* d_ws, size_t ws_size,
                              hipStream_t stream)
{
    (void)in_sizes; (void)n_in; (void)out_size; (void)ws_size;
    const float* inputs  = (const float*)d_in[0];
    const float* hx      = (const float*)d_in[1];
    const int*   sup_rows= (const int*)d_in[2];
    const int*   sup_cols= (const int*)d_in[3];
    const float* sup_vals= (const float*)d_in[4];
    const float* W_ru    = (const float*)d_in[5];
    const float* b_ru    = (const float*)d_in[6];
    const float* W_c     = (const float*)d_in[7];
    const float* b_c     = (const float*)d_in[8];
    float* out = (float*)d_out;

    char* ws = (char*)d_ws;
    float* xs = (float*)ws;                                 // 5 f32 buffers (half batch)
    size_t off = 5ull * 34603008ull;                        // 173,015,040
    ushort* wru_hi = (ushort*)(ws + off); off += 90112;
    ushort* wru_lo = (ushort*)(ws + off); off += 90112;
    ushort* wc_hi  = (ushort*)(ws + off); off += 45056;
    ushort* wc_lo  = (ushort*)(ws + off); off += 45056;
    int* row_ptr   = (int*)(ws + off);    off += 32800;     // 2*4097*4 rounded up
    int* cntfill   = (int*)(ws + off);    off += 65536;     // cnt[8192] + fill[8192]
    int* scols     = (int*)(ws + off);    off += 524288;
    float* svals   = (float*)(ws + off);  off += 524288;

    float* xs0 = xs;
    float* xs1 = xs + 1 * XSW;
    float* xs2 = xs + 2 * XSW;
    float* xs3 = xs + 3 * XSW;
    float* xs4 = xs + 4 * XSW;
    int* fill = cntfill + 8192;

    zero_k<<<64, 256, 0, stream>>>(cntfill);
    wtbuild_k<<<264, 256, 0, stream>>>(W_ru, W_c, wru_hi, wru_lo, wc_hi, wc_lo);
    count_k<<<512, 256, 0, stream>>>(sup_rows, cntfill);
    scan_k<<<2, 1024, 0, stream>>>(cntfill, row_ptr);
    scatter_k<<<512, 256, 0, stream>>>(sup_rows, sup_cols, sup_vals, row_ptr, fill, scols, svals);

    for (int h = 0; h < 2; ++h) {
        x0build_k<<<16896, 256, 0, stream>>>(inputs, hx, xs0, h);
        // gconv1 diffusion: step1 (both supports read xs0), step2 split per support
        spmm_k<<<dim3(8192, 2), 256, 0, stream>>>(xs0, xs0, xs1, xs3, xs0, row_ptr, scols, svals, 0, 0);
        spmm_k<<<dim3(8192, 1), 256, 0, stream>>>(xs1, xs1, xs2, xs2, xs0, row_ptr, scols, svals, 1, 0);
        spmm_k<<<dim3(8192, 1), 256, 0, stream>>>(xs3, xs3, xs4, xs4, xs0, row_ptr, scols, svals, 1, 1);
        // gconv1 matmul: u -> out, r*hx -> xs0 state part
        mm_ru_k<<<NN, 256, 0, stream>>>(xs, wru_hi, wru_lo, b_ru, hx, out, xs0, h);
        // gconv2 diffusion (xs0 now holds [inputs, r*hx])
        spmm_k<<<dim3(8192, 2), 256, 0, stream>>>(xs0, xs0, xs1, xs3, xs0, row_ptr, scols, svals, 0, 0);
        spmm_k<<<dim3(8192, 1), 256, 0, stream>>>(xs1, xs1, xs2, xs2, xs0, row_ptr, scols, svals, 1, 0);
        spmm_k<<<dim3(8192, 1), 256, 0, stream>>>(xs3, xs3, xs4, xs4, xs0, row_ptr, scols, svals, 1, 1);
        // gconv2 matmul + tanh + final GRU combine
        mm_c_k<<<NN, 256, 0, stream>>>(xs, wc_hi, wc_lo, b_c, hx, out, h);
    }
}